// Round 7
// baseline (94.212 us; speedup 1.0000x reference)
//
#include <hip/hip_runtime.h>

// Reference returns (x, y) unchanged — _block_scores is computed and discarded.
// d_out = concat(flat(x), flat(y)) in float32. Pure D2D copy, memory-bound.
// 268 MB read + 268 MB write; working set (537 MB) > L3 (256 MB) -> stream
// with nontemporal load/store. Flat launch, 2 float4 per range per thread
// (64B/thread total): 4 independent nt loads in flight before any store,
// no loop bookkeeping. 16384 blocks x 256 threads.

typedef float f4 __attribute__((ext_vector_type(4)));

__global__ __launch_bounds__(256)
void copy_xy_kernel(const f4* __restrict__ x, const f4* __restrict__ y,
                    f4* __restrict__ ox, f4* __restrict__ oy,
                    size_t n4) {
    // Each thread handles elements i0 and i0 + 256 (next block-sized chunk),
    // pattern: block b covers [b*512, b*512+512) in two coalesced halves.
    const size_t base = (size_t)blockIdx.x * 512 + threadIdx.x;
    const size_t i0 = base;
    const size_t i1 = base + 256;
    if (i1 < n4) {
        f4 a0 = __builtin_nontemporal_load(&x[i0]);
        f4 a1 = __builtin_nontemporal_load(&x[i1]);
        f4 b0 = __builtin_nontemporal_load(&y[i0]);
        f4 b1 = __builtin_nontemporal_load(&y[i1]);
        __builtin_nontemporal_store(a0, &ox[i0]);
        __builtin_nontemporal_store(a1, &ox[i1]);
        __builtin_nontemporal_store(b0, &oy[i0]);
        __builtin_nontemporal_store(b1, &oy[i1]);
    } else if (i0 < n4) {
        f4 a0 = __builtin_nontemporal_load(&x[i0]);
        f4 b0 = __builtin_nontemporal_load(&y[i0]);
        __builtin_nontemporal_store(a0, &ox[i0]);
        __builtin_nontemporal_store(b0, &oy[i0]);
    }
}

extern "C" void kernel_launch(void* const* d_in, const int* in_sizes, int n_in,
                              void* d_out, int out_size, void* d_ws, size_t ws_size,
                              hipStream_t stream) {
    const size_t nx = (size_t)in_sizes[0];  // x: 128*64*64*64 f32
    const size_t ny = (size_t)in_sizes[1];  // y: same count
    const size_t n4 = nx / 4;               // 8388608 float4 per range

    const f4* x = (const f4*)d_in[0];
    const f4* y = (const f4*)d_in[1];
    f4* ox = (f4*)d_out;
    f4* oy = (f4*)((char*)d_out + nx * sizeof(float));

    const int blocks = (int)((n4 + 511) / 512);  // 16384
    copy_xy_kernel<<<blocks, 256, 0, stream>>>(x, y, ox, oy, n4);
}